// Round 1
// baseline (3831.840 us; speedup 1.0000x reference)
//
#include <hip/hip_runtime.h>

typedef _Float16 f16;
typedef _Float16 f16x2 __attribute__((ext_vector_type(2)));
typedef _Float16 f16x4 __attribute__((ext_vector_type(4)));
typedef _Float16 f16x8 __attribute__((ext_vector_type(8)));
typedef float f32x4 __attribute__((ext_vector_type(4)));

#define N_ 256
#define T_ 64
#define D_ 1024
#define H_ 1024
#define K3 3072
#define G4 4096
#define NBLK 256

// ---------------- transpose Wx/Wh/Wattn (fp32, [k][j]) -> W3T (fp16, [j][k]) -----
__global__ void k_transpose(const float* __restrict__ Wx, const float* __restrict__ Wh,
                            const float* __restrict__ Wattn, f16* __restrict__ W3T) {
    __shared__ float tile[32][33];
    int j0 = blockIdx.x * 32;   // 128 blocks over j (4096)
    int k0 = blockIdx.y * 32;   // 96 blocks over k (3072)
    int tx = threadIdx.x;       // 32
    int ty = threadIdx.y;       // 8
    for (int i = 0; i < 4; i++) {
        int k = k0 + ty + i * 8;
        const float* W = (k < 1024) ? Wx : ((k < 2048) ? Wh : Wattn);
        int kr = k & 1023;
        tile[ty + i * 8][tx] = W[(size_t)kr * 4096 + j0 + tx];
    }
    __syncthreads();
    for (int i = 0; i < 4; i++) {
        int j = j0 + ty + i * 8;
        W3T[(size_t)j * K3 + k0 + tx] = (f16)tile[tx][ty + i * 8];
    }
}

// ---------------- cast A (fp32) -> A16 (f16) -------------------------------------
__global__ void k_castA(const float* __restrict__ A, f16* __restrict__ A16) {
    int i = blockIdx.x * 256 + threadIdx.x;
    float4 v = ((const float4*)A)[i];
    f16x4 h4 = {(f16)v.x, (f16)v.y, (f16)v.z, (f16)v.w};
    ((f16x4*)A16)[i] = h4;
}

// ---------------- cast x (fp32) -> x16 (f16), 8 elems/thread ---------------------
__global__ void k_castX(const float* __restrict__ x, f16* __restrict__ x16) {
    size_t i = (size_t)blockIdx.x * 2048 + (size_t)threadIdx.x * 8;
    float4 v0 = *(const float4*)(x + i);
    float4 v1 = *(const float4*)(x + i + 4);
    f16x8 h;
    h[0] = (f16)v0.x; h[1] = (f16)v0.y; h[2] = (f16)v0.z; h[3] = (f16)v0.w;
    h[4] = (f16)v1.x; h[5] = (f16)v1.y; h[6] = (f16)v1.z; h[7] = (f16)v1.w;
    *(f16x8*)(x16 + i) = h;
}

// ---------------- init: h0 = c0 = mean(A); spart[0][n][:] = h0.A; zero rest ------
__global__ void k_init(const float* __restrict__ A, f16* __restrict__ Zh,
                       float* __restrict__ c, float* __restrict__ spart,
                       int* __restrict__ bar) {
    int n = blockIdx.x;
    int tid = threadIdx.x;
    if (n == 0 && tid == 0) { bar[0] = 0; bar[32] = 0; }   // cnt, gen
    __shared__ float sred[256][16];
    float s[16];
#pragma unroll
    for (int l = 0; l < 16; l++) s[l] = 0.f;
    for (int i = 0; i < 4; i++) {
        int h = tid + i * 256;
        const float* Ap = A + (size_t)n * 16384 + h * 16;
        float a[16];
        float sum = 0.f;
#pragma unroll
        for (int l = 0; l < 16; l++) { a[l] = Ap[l]; sum += a[l]; }
        float h0 = sum * (1.f / 16.f);
        c[n * 1024 + h] = h0;
        Zh[n * 1024 + h] = (f16)h0;
#pragma unroll
        for (int l = 0; l < 16; l++) s[l] += h0 * a[l];
    }
#pragma unroll
    for (int l = 0; l < 16; l++) sred[tid][l] = s[l];
    __syncthreads();
    for (int st = 128; st > 0; st >>= 1) {
        if (tid < st) {
#pragma unroll
            for (int l = 0; l < 16; l++) sred[tid][l] += sred[tid + st][l];
        }
        __syncthreads();
    }
    if (tid < 16) spart[(size_t)n * 16 + tid] = sred[0][tid];   // slab ht=0
    // zero slabs ht=1..63 for this n: 1008 entries
    for (int i = 0; i < 4; i++) {
        int idx = tid * 4 + i;
        if (idx < 1008) {
            int ht = 1 + (idx >> 4);
            int l = idx & 15;
            spart[((size_t)ht * 256 + n) * 16 + l] = 0.f;
        }
    }
}

// ---------------- persistent kernel: all 64 steps, device-scope barriers ---------
// grid 256 = 1 block/CU (LDS 76 KB), co-resident. Per step:
//   phase A: block n computes softmax + Za[n] (512 thr)
//   barrier1: split arrive/wait — arrive after Za publish, compute the x- and
//             h- K-segments (2/3 of GEMM, Za-independent), THEN wait, then the
//             attn K-segment. K re-balanced: wave w owns subtiles [w*128,w*128+128)
//             of EACH 1024-wide segment, so every wave hides the wait equally.
//   phase B epilogue: slab-reduce, gates, state update, spart for next step
//   barrier2: blocking (spart/Zh publish)
__global__ __launch_bounds__(512, 2) void k_persist(
    const f16* __restrict__ x16, const f16* __restrict__ W3T,
    f16* __restrict__ Zh0, f16* __restrict__ Zh1,
    f16* __restrict__ Za, const f16* __restrict__ A16,
    const float* __restrict__ b, float* __restrict__ c,
    float* __restrict__ spart, float* __restrict__ out,
    int* bar) {
    __shared__ float Gs[4][4][64 * 17];   // 69.6 KB
    __shared__ float Hs[64 * 17];         //  4.4 KB
    __shared__ float sredA[32][17];       //  2.2 KB
    __shared__ float sfinA[16];

    int tid = threadIdx.x;
    int wave = tid >> 6;
    int lane = tid & 63;
    int m16 = lane & 15;
    int quad = lane >> 4;
    int bid = blockIdx.x;
    int ht = bid & 63;
    int n0 = (bid >> 6) << 6;
    int hc = ht * 16;
    int* cnt = bar;         // separate 128B lines
    int* gen = bar + 32;
    int bgen = 0;           // local generation: gen goes bgen -> bgen+1 each barrier

    const f16* brow[4];
#pragma unroll
    for (int g = 0; g < 4; g++)
        brow[g] = W3T + (size_t)(g * 1024 + hc + m16) * K3 + quad * 8;

    size_t offx[4], offz[4];
#pragma unroll
    for (int mt = 0; mt < 4; mt++) {
        int n = n0 + mt * 16 + m16;
        offx[mt] = (size_t)n * (T_ * 1024);
        offz[mt] = (size_t)n * 1024;
    }
    int kb = wave * 128;

    for (int t = 0; t < T_; t++) {
        const f16* Zin = (t & 1) ? Zh1 : Zh0;
        f16* Zout = (t & 1) ? Zh0 : Zh1;

        // ===== phase A: attention for n = bid =====
        {
            int ga = tid >> 4;            // 0..31
            int l = tid & 15;
            sredA[ga][l] = spart[((size_t)ga * 256 + bid) * 16 + l]
                         + spart[((size_t)(ga + 32) * 256 + bid) * 16 + l];
        }
        __syncthreads();
        if (tid < 16) {
            float s = 0.f;
#pragma unroll
            for (int gg = 0; gg < 32; gg++) s += sredA[gg][tid];
            sfinA[tid] = s;
        }
        __syncthreads();
        {
            float w[16];
            float mx = -1e30f;
#pragma unroll
            for (int ll = 0; ll < 16; ll++) { w[ll] = sfinA[ll] * 0.03125f; mx = fmaxf(mx, w[ll]); }
            float sum = 0.f;
#pragma unroll
            for (int ll = 0; ll < 16; ll++) { w[ll] = __expf(w[ll] - mx); sum += w[ll]; }
            float inv = 1.f / sum;
            const f16* Ap = A16 + (size_t)bid * 16384 + (size_t)tid * 32;  // h = 2*tid
            f16x2 za2;
#pragma unroll
            for (int i = 0; i < 2; i++) {
                f16x8 a0 = *(const f16x8*)(Ap + i * 16);
                f16x8 a1 = *(const f16x8*)(Ap + i * 16 + 8);
                float acc = 0.f;
#pragma unroll
                for (int ll = 0; ll < 8; ll++)
                    acc += (float)a0[ll] * w[ll] + (float)a1[ll] * w[ll + 8];
                za2[i] = (f16)(acc * inv);
            }
            *(f16x2*)(Za + bid * 1024 + tid * 2) = za2;
        }

        // ===== barrier 1: arrive now (Za published), wait deferred =====
        __syncthreads();
        if (tid == 0) {
            __builtin_amdgcn_fence(__ATOMIC_RELEASE, "agent");
            int old = __hip_atomic_fetch_add(cnt, 1, __ATOMIC_RELAXED, __HIP_MEMORY_SCOPE_AGENT);
            if (old == NBLK - 1) {
                __hip_atomic_store(cnt, 0, __ATOMIC_RELAXED, __HIP_MEMORY_SCOPE_AGENT);
                __hip_atomic_store(gen, bgen + 1, __ATOMIC_RELEASE, __HIP_MEMORY_SCOPE_AGENT);
            }
        }

        // ===== phase B: GEMM, Za-independent segments first =====
        f32x4 acc[4][4];
#pragma unroll
        for (int g = 0; g < 4; g++)
#pragma unroll
            for (int m = 0; m < 4; m++) acc[g][m] = (f32x4){0.f, 0.f, 0.f, 0.f};

        const f16* xb = x16 + (size_t)t * 1024 + kb + quad * 8;
        const f16* hb = Zin + kb + quad * 8;
        const f16* ab = Za + kb + quad * 8;

#pragma unroll 2
        for (int j = 0; j < 4; j++) {               // x @ Wx slice
            int k = j * 32;
            f16x8 a[4], bb[4];
#pragma unroll
            for (int mt = 0; mt < 4; mt++) a[mt] = *(const f16x8*)(xb + offx[mt] + k);
#pragma unroll
            for (int g = 0; g < 4; g++) bb[g] = *(const f16x8*)(brow[g] + kb + k);
#pragma unroll
            for (int g = 0; g < 4; g++)
#pragma unroll
                for (int mt = 0; mt < 4; mt++)
                    acc[g][mt] = __builtin_amdgcn_mfma_f32_16x16x32_f16(a[mt], bb[g], acc[g][mt], 0, 0, 0);
        }
#pragma unroll 2
        for (int j = 0; j < 4; j++) {               // h @ Wh slice
            int k = j * 32;
            f16x8 a[4], bb[4];
#pragma unroll
            for (int mt = 0; mt < 4; mt++) a[mt] = *(const f16x8*)(hb + offz[mt] + k);
#pragma unroll
            for (int g = 0; g < 4; g++) bb[g] = *(const f16x8*)(brow[g] + 1024 + kb + k);
#pragma unroll
            for (int g = 0; g < 4; g++)
#pragma unroll
                for (int mt = 0; mt < 4; mt++)
                    acc[g][mt] = __builtin_amdgcn_mfma_f32_16x16x32_f16(a[mt], bb[g], acc[g][mt], 0, 0, 0);
        }

        // deferred wait: all blocks' Za published (hidden under the 8 subtiles above)
        while (__hip_atomic_load(gen, __ATOMIC_RELAXED, __HIP_MEMORY_SCOPE_AGENT) == bgen)
            __builtin_amdgcn_s_sleep(1);
        __builtin_amdgcn_fence(__ATOMIC_ACQUIRE, "agent");
        bgen++;

#pragma unroll 2
        for (int j = 0; j < 4; j++) {               // attn @ Wattn slice
            int k = j * 32;
            f16x8 a[4], bb[4];
#pragma unroll
            for (int mt = 0; mt < 4; mt++) a[mt] = *(const f16x8*)(ab + offz[mt] + k);
#pragma unroll
            for (int g = 0; g < 4; g++) bb[g] = *(const f16x8*)(brow[g] + 2048 + kb + k);
#pragma unroll
            for (int g = 0; g < 4; g++)
#pragma unroll
                for (int mt = 0; mt < 4; mt++)
                    acc[g][mt] = __builtin_amdgcn_mfma_f32_16x16x32_f16(a[mt], bb[g], acc[g][mt], 0, 0, 0);
        }

        // ===== reduce 8 K-slice waves via 4 slabs: write then owner-add =====
        if (wave < 4) {
#pragma unroll
            for (int g = 0; g < 4; g++)
#pragma unroll
                for (int mt = 0; mt < 4; mt++)
#pragma unroll
                    for (int r = 0; r < 4; r++)
                        Gs[wave][g][(mt * 16 + quad * 4 + r) * 17 + m16] = acc[g][mt][r];
        }
        __syncthreads();
        if (wave >= 4) {
            int sl = wave - 4;
#pragma unroll
            for (int g = 0; g < 4; g++)
#pragma unroll
                for (int mt = 0; mt < 4; mt++)
#pragma unroll
                    for (int r = 0; r < 4; r++)
                        Gs[sl][g][(mt * 16 + quad * 4 + r) * 17 + m16] += acc[g][mt][r];
        }
        __syncthreads();

        // ===== gates + state update: 64n x 16h = 1024, 2 per thread =====
#pragma unroll
        for (int i = 0; i < 2; i++) {
            int idx = i * 512 + tid;
            int nn = idx >> 4;
            int hh = idx & 15;
            int gi = nn * 17 + hh;
            int gn = n0 + nn;
            int gh = hc + hh;
            float ai = Gs[0][0][gi] + Gs[1][0][gi] + Gs[2][0][gi] + Gs[3][0][gi] + b[gh];
            float af = Gs[0][1][gi] + Gs[1][1][gi] + Gs[2][1][gi] + Gs[3][1][gi] + b[1024 + gh];
            float ao = Gs[0][2][gi] + Gs[1][2][gi] + Gs[2][2][gi] + Gs[3][2][gi] + b[2048 + gh];
            float ag = Gs[0][3][gi] + Gs[1][3][gi] + Gs[2][3][gi] + Gs[3][3][gi] + b[3072 + gh];
            float ig = 1.f / (1.f + __expf(-ai));
            float fg = 1.f / (1.f + __expf(-af));
            float og = 1.f / (1.f + __expf(-ao));
            float gg = tanhf(ag);
            float cn = fg * c[gn * 1024 + gh] + ig * gg;
            c[gn * 1024 + gh] = cn;
            float hn = og * tanhf(cn);
            out[((size_t)gn * T_ + t) * 1024 + gh] = hn;
            Zout[gn * 1024 + gh] = (f16)hn;
            Hs[gi] = hn;
        }
        __syncthreads();

        // ===== partial scores vs local A16 slice: 64n x 16l, 2 per thread =====
#pragma unroll
        for (int i = 0; i < 2; i++) {
            int idx = i * 512 + tid;
            int nn = idx >> 4;
            int l = idx & 15;
            int gn = n0 + nn;
            const f16* Ap = A16 + (size_t)gn * 16384 + hc * 16 + l;
            float s = 0.f;
#pragma unroll
            for (int hh = 0; hh < 16; hh++)
                s += Hs[nn * 17 + hh] * (float)Ap[hh * 16];
            spart[((size_t)ht * 256 + gn) * 16 + l] = s;
        }

        // ===== barrier 2 (blocking): spart/Zout published =====
        __syncthreads();
        if (tid == 0) {
            __builtin_amdgcn_fence(__ATOMIC_RELEASE, "agent");
            int old = __hip_atomic_fetch_add(cnt, 1, __ATOMIC_RELAXED, __HIP_MEMORY_SCOPE_AGENT);
            if (old == NBLK - 1) {
                __hip_atomic_store(cnt, 0, __ATOMIC_RELAXED, __HIP_MEMORY_SCOPE_AGENT);
                __hip_atomic_store(gen, bgen + 1, __ATOMIC_RELEASE, __HIP_MEMORY_SCOPE_AGENT);
            } else {
                while (__hip_atomic_load(gen, __ATOMIC_RELAXED, __HIP_MEMORY_SCOPE_AGENT) == bgen)
                    __builtin_amdgcn_s_sleep(2);
            }
            __builtin_amdgcn_fence(__ATOMIC_ACQUIRE, "agent");
        }
        __syncthreads();
        bgen++;
    }
}

extern "C" void kernel_launch(void* const* d_in, const int* in_sizes, int n_in,
                              void* d_out, int out_size, void* d_ws, size_t ws_size,
                              hipStream_t stream) {
    const float* x     = (const float*)d_in[0];
    const float* A     = (const float*)d_in[1];
    const float* Wx    = (const float*)d_in[2];
    const float* Wh    = (const float*)d_in[3];
    const float* Wattn = (const float*)d_in[4];
    const float* b     = (const float*)d_in[5];
    float* out = (float*)d_out;

    char* ws = (char*)d_ws;
    size_t off = 0;
    f16* W3T = (f16*)(ws + off); off += (size_t)G4 * K3 * 2;        // 25.2 MB
    f16* x16 = (f16*)(ws + off); off += (size_t)N_ * T_ * D_ * 2;   // 33.6 MB
    f16* A16 = (f16*)(ws + off); off += (size_t)N_ * H_ * 16 * 2;   // 8.4 MB
    f16* Zh0 = (f16*)(ws + off); off += (size_t)N_ * H_ * 2;
    f16* Zh1 = (f16*)(ws + off); off += (size_t)N_ * H_ * 2;
    f16* Za  = (f16*)(ws + off); off += (size_t)N_ * H_ * 2;
    float* c = (float*)(ws + off); off += (size_t)N_ * H_ * 4;      // 1 MB
    float* spart = (float*)(ws + off); off += (size_t)64 * N_ * 16 * 4; // 1 MB
    int* bar = (int*)(ws + off); off += 256;                        // cnt @+0, gen @+32

    k_transpose<<<dim3(128, 96), dim3(32, 8), 0, stream>>>(Wx, Wh, Wattn, W3T);
    k_castA<<<4096, 256, 0, stream>>>(A, A16);
    k_castX<<<8192, 256, 0, stream>>>(x, x16);
    k_init<<<256, 256, 0, stream>>>(A, Zh0, c, spart, bar);
    k_persist<<<256, 512, 0, stream>>>(x16, W3T, Zh0, Zh1, Za, A16, b, c, spart, out, bar);
}

// Round 4
// 2327.482 us; speedup vs baseline: 1.6463x; 1.6463x over previous
//
#include <hip/hip_runtime.h>

typedef _Float16 f16;
typedef _Float16 f16x2 __attribute__((ext_vector_type(2)));
typedef _Float16 f16x4 __attribute__((ext_vector_type(4)));
typedef _Float16 f16x8 __attribute__((ext_vector_type(8)));
typedef float f32x4 __attribute__((ext_vector_type(4)));

#define N_ 256
#define T_ 64
#define D_ 1024
#define H_ 1024
#define K3 3072
#define G4 4096

// ---------------- transpose Wx/Wh/Wattn (fp32, [k][j]) -> W3T (fp16, [j][k]) -----
__global__ void k_transpose(const float* __restrict__ Wx, const float* __restrict__ Wh,
                            const float* __restrict__ Wattn, f16* __restrict__ W3T) {
    __shared__ float tile[32][33];
    int j0 = blockIdx.x * 32;   // 128 blocks over j (4096)
    int k0 = blockIdx.y * 32;   // 96 blocks over k (3072)
    int tx = threadIdx.x;       // 32
    int ty = threadIdx.y;       // 8
    for (int i = 0; i < 4; i++) {
        int k = k0 + ty + i * 8;
        const float* W = (k < 1024) ? Wx : ((k < 2048) ? Wh : Wattn);
        int kr = k & 1023;
        tile[ty + i * 8][tx] = W[(size_t)kr * 4096 + j0 + tx];
    }
    __syncthreads();
    for (int i = 0; i < 4; i++) {
        int j = j0 + ty + i * 8;
        W3T[(size_t)j * K3 + k0 + tx] = (f16)tile[tx][ty + i * 8];
    }
}

// ---------------- cast A (fp32) -> A16 (f16), layout [n][h][l] -------------------
__global__ void k_castA(const float* __restrict__ A, f16* __restrict__ A16) {
    int i = blockIdx.x * 256 + threadIdx.x;
    float4 v = ((const float4*)A)[i];
    f16x4 h4 = {(f16)v.x, (f16)v.y, (f16)v.z, (f16)v.w};
    ((f16x4*)A16)[i] = h4;
}

// ---------------- cast x (fp32) -> x16 (f16), 8 elems/thread ---------------------
__global__ void k_castX(const float* __restrict__ x, f16* __restrict__ x16) {
    size_t i = (size_t)blockIdx.x * 2048 + (size_t)threadIdx.x * 8;
    float4 v0 = *(const float4*)(x + i);
    float4 v1 = *(const float4*)(x + i + 4);
    f16x8 h;
    h[0] = (f16)v0.x; h[1] = (f16)v0.y; h[2] = (f16)v0.z; h[3] = (f16)v0.w;
    h[4] = (f16)v1.x; h[5] = (f16)v1.y; h[6] = (f16)v1.z; h[7] = (f16)v1.w;
    *(f16x8*)(x16 + i) = h;
}

// ---------------- A (fp32 [n][h][l]) -> AT16 (f16 [n][l][h]) ---------------------
__global__ void k_castAT(const float* __restrict__ A, f16* __restrict__ AT16) {
    __shared__ f16 sA[16 * 1024];
    int n = blockIdx.x;
    int tid = threadIdx.x;
    for (int i = 0; i < 4; i++) {
        int h = tid + i * 256;
        const float* Ap = A + (size_t)n * 16384 + h * 16;
        float4 v0 = ((const float4*)Ap)[0];
        float4 v1 = ((const float4*)Ap)[1];
        float4 v2 = ((const float4*)Ap)[2];
        float4 v3 = ((const float4*)Ap)[3];
        float vv[16] = {v0.x, v0.y, v0.z, v0.w, v1.x, v1.y, v1.z, v1.w,
                        v2.x, v2.y, v2.z, v2.w, v3.x, v3.y, v3.z, v3.w};
#pragma unroll
        for (int l = 0; l < 16; l++) sA[l * 1024 + h] = (f16)vv[l];
    }
    __syncthreads();
    for (int i = 0; i < 8; i++) {
        int cnk = tid + i * 256;     // 2048 chunks of 8 f16
        f16x8 v = *(const f16x8*)(sA + cnk * 8);
        *(f16x8*)(AT16 + (size_t)n * 16384 + cnk * 8) = v;
    }
}

// ---------------- precompute PT16[n][j][l] = sum_h A[n,h,l] * Wattn[h,j] ---------
// grid 256 = 8 n-groups(32) x 32 j-tiles(128); 8 waves, wave w -> 16-col tile.
__global__ __launch_bounds__(512) void k_precompP(
    const f16* __restrict__ AT16, const f16* __restrict__ W3T,
    f16* __restrict__ PT16) {
    int tid = threadIdx.x;
    int wave = tid >> 6;
    int lane = tid & 63;
    int m16 = lane & 15;
    int quad = lane >> 4;
    int bid = blockIdx.x;
    int jb = bid & 31;
    int nb = bid >> 5;
    int j0 = jb * 128 + wave * 16;

    const f16* bp = W3T + (size_t)(j0 + m16) * K3 + 2048 + quad * 8;
    for (int np = 0; np < 16; np++) {
        int n = nb * 32 + np * 2;
        const f16* a0p = AT16 + (size_t)n * 16384 + m16 * 1024 + quad * 8;
        const f16* a1p = a0p + 16384;
        f32x4 ac0 = {0.f, 0.f, 0.f, 0.f};
        f32x4 ac1 = {0.f, 0.f, 0.f, 0.f};
#pragma unroll 4
        for (int ks = 0; ks < 32; ks++) {
            int k = ks * 32;
            f16x8 bb = *(const f16x8*)(bp + k);
            f16x8 a0 = *(const f16x8*)(a0p + k);
            f16x8 a1 = *(const f16x8*)(a1p + k);
            ac0 = __builtin_amdgcn_mfma_f32_16x16x32_f16(a0, bb, ac0, 0, 0, 0);
            ac1 = __builtin_amdgcn_mfma_f32_16x16x32_f16(a1, bb, ac1, 0, 0, 0);
        }
        // C layout: col = m16 (j), row = quad*4 + r (l). Store 4 f16 (8B) per lane.
        f16x4 o0 = {(f16)ac0[0], (f16)ac0[1], (f16)ac0[2], (f16)ac0[3]};
        f16x4 o1 = {(f16)ac1[0], (f16)ac1[1], (f16)ac1[2], (f16)ac1[3]};
        *(f16x4*)(PT16 + (size_t)n * 65536 + (size_t)(j0 + m16) * 16 + quad * 4) = o0;
        *(f16x4*)(PT16 + (size_t)(n + 1) * 65536 + (size_t)(j0 + m16) * 16 + quad * 4) = o1;
    }
}

// ---------------- init: h0 = c0 = mean(A); Sc0[n][:] = h0.A; zero Sc1/Sc2 --------
__global__ void k_init(const float* __restrict__ A, f16* __restrict__ Zh,
                       float* __restrict__ c, float* __restrict__ Sc0,
                       float* __restrict__ Sc1, float* __restrict__ Sc2) {
    int n = blockIdx.x;
    int tid = threadIdx.x;
    __shared__ float sred[256][16];
    float s[16];
#pragma unroll
    for (int l = 0; l < 16; l++) s[l] = 0.f;
    for (int i = 0; i < 4; i++) {
        int h = tid + i * 256;
        const float* Ap = A + (size_t)n * 16384 + h * 16;
        float a[16];
        float sum = 0.f;
#pragma unroll
        for (int l = 0; l < 16; l++) { a[l] = Ap[l]; sum += a[l]; }
        float h0 = sum * (1.f / 16.f);
        c[n * 1024 + h] = h0;
        Zh[n * 1024 + h] = (f16)h0;
#pragma unroll
        for (int l = 0; l < 16; l++) s[l] += h0 * a[l];
    }
#pragma unroll
    for (int l = 0; l < 16; l++) sred[tid][l] = s[l];
    __syncthreads();
    for (int st = 128; st > 0; st >>= 1) {
        if (tid < st) {
#pragma unroll
            for (int l = 0; l < 16; l++) sred[tid][l] += sred[tid + st][l];
        }
        __syncthreads();
    }
    if (tid < 16) {
        Sc0[n * 16 + tid] = sred[0][tid];
        Sc1[n * 16 + tid] = 0.f;
        Sc2[n * 16 + tid] = 0.f;
    }
}

// ---------------- one LSTM step: softmax + GEMM(K=2048) + P-dot + state ----------
// grid 256 = 4 n0(64) x 64 ht(16 h-cols); block 512 = 8 waves.
// Rbuf: reduced scores for THIS step (complete; written by dispatch t-1).
// Wbuf: accumulate partial scores for step t+1 (atomicAdd, device scope).
// Zbuf: zeroed here; it is Wbuf of step t+1. All ordering via dispatch boundaries.
// GEMM: waves 0-3 own x@Wx K-slices, waves 4-7 own h@Wh K-slices (256 K each).
// attn@Wattn is replaced by att(n,j) = sum_l w[n,l]*PT16[n][j][l] in the epilogue.
__global__ __launch_bounds__(512, 2) void k_step(
    const f16* __restrict__ x16, const f16* __restrict__ W3T,
    const f16* __restrict__ Zin, f16* __restrict__ Zout,
    const f16* __restrict__ A16, const f16* __restrict__ PT16,
    const float* __restrict__ b, float* __restrict__ c,
    const float* __restrict__ Rbuf, float* __restrict__ Wbuf,
    float* __restrict__ Zbuf, float* __restrict__ out, int t) {
    __shared__ float Gs[4][4][64 * 17];   // 69.6 KB
    __shared__ float Hs[64 * 17];         //  4.4 KB
    __shared__ float Ws[64][17];          //  4.4 KB softmax weights

    int tid = threadIdx.x;
    int wave = tid >> 6;
    int lane = tid & 63;
    int m16 = lane & 15;
    int quad = lane >> 4;
    int bid = blockIdx.x;
    int ht = bid & 63;
    int n0 = (bid >> 6) << 6;
    int hc = ht * 16;

    // ---- phase A: softmax of reduced scores (64 threads, one n each) ----
    if (tid < 64) {
        const float* rp = Rbuf + (size_t)(n0 + tid) * 16;
        float4 q0 = ((const float4*)rp)[0];
        float4 q1 = ((const float4*)rp)[1];
        float4 q2 = ((const float4*)rp)[2];
        float4 q3 = ((const float4*)rp)[3];
        float v[16] = {q0.x, q0.y, q0.z, q0.w, q1.x, q1.y, q1.z, q1.w,
                       q2.x, q2.y, q2.z, q2.w, q3.x, q3.y, q3.z, q3.w};
        float mx = -1e30f;
#pragma unroll
        for (int l = 0; l < 16; l++) { v[l] *= 0.03125f; mx = fmaxf(mx, v[l]); }
        float sum = 0.f;
#pragma unroll
        for (int l = 0; l < 16; l++) { v[l] = __expf(v[l] - mx); sum += v[l]; }
        float inv = 1.f / sum;
#pragma unroll
        for (int l = 0; l < 16; l++) Ws[tid][l] = v[l] * inv;
    }
    // zero this block's row of the t+2 score buffer (nobody touches it this step)
    if (tid < 16) Zbuf[bid * 16 + tid] = 0.f;

    // ---- GEMM K=2048: waves 0-3 x-segment, waves 4-7 h-segment ----
    f32x4 acc[4][4];
#pragma unroll
    for (int g = 0; g < 4; g++)
#pragma unroll
        for (int m = 0; m < 4; m++) acc[g][m] = (f32x4){0.f, 0.f, 0.f, 0.f};

    int kb = (wave & 3) * 256;
    const f16* ab;
    size_t aoff[4];
    int bc0;
    if (wave < 4) {
        ab = x16 + (size_t)t * 1024 + kb + quad * 8;
#pragma unroll
        for (int mt = 0; mt < 4; mt++)
            aoff[mt] = (size_t)(n0 + mt * 16 + m16) * (T_ * 1024);
        bc0 = kb;
    } else {
        ab = Zin + kb + quad * 8;
#pragma unroll
        for (int mt = 0; mt < 4; mt++)
            aoff[mt] = (size_t)(n0 + mt * 16 + m16) * 1024;
        bc0 = 1024 + kb;
    }
    const f16* brow[4];
#pragma unroll
    for (int g = 0; g < 4; g++)
        brow[g] = W3T + (size_t)(g * 1024 + hc + m16) * K3 + bc0 + quad * 8;

#pragma unroll 2
    for (int s = 0; s < 8; s++) {
        int k = s * 32;
        f16x8 a[4], bb[4];
#pragma unroll
        for (int mt = 0; mt < 4; mt++) a[mt] = *(const f16x8*)(ab + aoff[mt] + k);
#pragma unroll
        for (int g = 0; g < 4; g++) bb[g] = *(const f16x8*)(brow[g] + k);
#pragma unroll
        for (int g = 0; g < 4; g++)
#pragma unroll
            for (int mt = 0; mt < 4; mt++)
                acc[g][mt] = __builtin_amdgcn_mfma_f32_16x16x32_f16(a[mt], bb[g], acc[g][mt], 0, 0, 0);
    }

    // ---- reduce 8 K-slice waves via 4 slabs: write then owner-add ----
    if (wave < 4) {
#pragma unroll
        for (int g = 0; g < 4; g++)
#pragma unroll
            for (int mt = 0; mt < 4; mt++)
#pragma unroll
                for (int r = 0; r < 4; r++)
                    Gs[wave][g][(mt * 16 + quad * 4 + r) * 17 + m16] = acc[g][mt][r];
    }
    __syncthreads();
    if (wave >= 4) {
        int sl = wave - 4;
#pragma unroll
        for (int g = 0; g < 4; g++)
#pragma unroll
            for (int mt = 0; mt < 4; mt++)
#pragma unroll
                for (int r = 0; r < 4; r++)
                    Gs[sl][g][(mt * 16 + quad * 4 + r) * 17 + m16] += acc[g][mt][r];
    }
    __syncthreads();

    // ---- gates + state: thread owns (nn, 2 adjacent h-cols) x 4 gates ----
    {
        int idx0 = tid * 2;
        int nn = idx0 >> 4;
        int hh0 = idx0 & 15;
        int gn = n0 + nn;
        int gh0 = hc + hh0;
        float wv[16];
#pragma unroll
        for (int l = 0; l < 16; l++) wv[l] = Ws[nn][l];
        // attention contribution via PT16: att(g,i) = sum_l wv[l]*PT[gn][g*1024+gh0+i][l]
        float att[4][2];
        const f16* pt = PT16 + (size_t)gn * 65536 + (size_t)gh0 * 16;
#pragma unroll
        for (int g = 0; g < 4; g++)
#pragma unroll
            for (int i = 0; i < 2; i++) {
                const f16* p = pt + ((size_t)g * 1024 + i) * 16;
                f16x8 p0 = *(const f16x8*)(p);
                f16x8 p1 = *(const f16x8*)(p + 8);
                float s = 0.f;
#pragma unroll
                for (int l = 0; l < 8; l++)
                    s += (float)p0[l] * wv[l] + (float)p1[l] * wv[l + 8];
                att[g][i] = s;
            }
        float hn2[2];
#pragma unroll
        for (int i = 0; i < 2; i++) {
            int gi = nn * 17 + hh0 + i;
            int gh = gh0 + i;
            float ai = Gs[0][0][gi] + Gs[1][0][gi] + Gs[2][0][gi] + Gs[3][0][gi] + b[gh] + att[0][i];
            float af = Gs[0][1][gi] + Gs[1][1][gi] + Gs[2][1][gi] + Gs[3][1][gi] + b[1024 + gh] + att[1][i];
            float ao = Gs[0][2][gi] + Gs[1][2][gi] + Gs[2][2][gi] + Gs[3][2][gi] + b[2048 + gh] + att[2][i];
            float ag = Gs[0][3][gi] + Gs[1][3][gi] + Gs[2][3][gi] + Gs[3][3][gi] + b[3072 + gh] + att[3][i];
            float ig = 1.f / (1.f + __expf(-ai));
            float fg = 1.f / (1.f + __expf(-af));
            float og = 1.f / (1.f + __expf(-ao));
            float gg = tanhf(ag);
            float cn = fg * c[gn * 1024 + gh] + ig * gg;
            c[gn * 1024 + gh] = cn;
            float hn = og * tanhf(cn);
            hn2[i] = hn;
            Hs[gi] = hn;
        }
        float2 o2 = {hn2[0], hn2[1]};
        *(float2*)(out + ((size_t)gn * T_ + t) * 1024 + gh0) = o2;
        f16x2 z2 = {(f16)hn2[0], (f16)hn2[1]};
        *(f16x2*)(Zout + gn * 1024 + gh0) = z2;
    }
    __syncthreads();

    // ---- partial scores vs local A16 slice -> atomicAdd into step-t+1 buffer ----
#pragma unroll
    for (int i = 0; i < 2; i++) {
        int idx = i * 512 + tid;
        int nn = idx >> 4;
        int l = idx & 15;
        int gn = n0 + nn;
        const f16* Ap = A16 + (size_t)gn * 16384 + hc * 16 + l;
        float s = 0.f;
#pragma unroll
        for (int hh = 0; hh < 16; hh++)
            s += Hs[nn * 17 + hh] * (float)Ap[hh * 16];
        atomicAdd(Wbuf + gn * 16 + l, s);
    }
}

extern "C" void kernel_launch(void* const* d_in, const int* in_sizes, int n_in,
                              void* d_out, int out_size, void* d_ws, size_t ws_size,
                              hipStream_t stream) {
    const float* x     = (const float*)d_in[0];
    const float* A     = (const float*)d_in[1];
    const float* Wx    = (const float*)d_in[2];
    const float* Wh    = (const float*)d_in[3];
    const float* Wattn = (const float*)d_in[4];
    const float* b     = (const float*)d_in[5];
    float* out = (float*)d_out;

    char* ws = (char*)d_ws;
    size_t off = 0;
    f16* W3T  = (f16*)(ws + off); off += (size_t)G4 * K3 * 2;         // 25.2 MB
    f16* x16  = (f16*)(ws + off); off += (size_t)N_ * T_ * D_ * 2;    // 33.6 MB
    f16* A16  = (f16*)(ws + off); off += (size_t)N_ * H_ * 16 * 2;    //  8.4 MB
    f16* AT16 = (f16*)(ws + off); off += (size_t)N_ * 16 * H_ * 2;    //  8.4 MB
    f16* PT16 = (f16*)(ws + off); off += (size_t)N_ * G4 * 16 * 2;    // 33.6 MB
    f16* Zh0  = (f16*)(ws + off); off += (size_t)N_ * H_ * 2;
    f16* Zh1  = (f16*)(ws + off); off += (size_t)N_ * H_ * 2;
    float* c  = (float*)(ws + off); off += (size_t)N_ * H_ * 4;       //  1 MB
    float* Sc0 = (float*)(ws + off); off += (size_t)N_ * 16 * 4;      // 16 KB
    float* Sc1 = (float*)(ws + off); off += (size_t)N_ * 16 * 4;
    float* Sc2 = (float*)(ws + off); off += (size_t)N_ * 16 * 4;
    float* Sc[3] = {Sc0, Sc1, Sc2};

    k_transpose<<<dim3(128, 96), dim3(32, 8), 0, stream>>>(Wx, Wh, Wattn, W3T);
    k_castA<<<4096, 256, 0, stream>>>(A, A16);
    k_castX<<<8192, 256, 0, stream>>>(x, x16);
    k_castAT<<<256, 256, 0, stream>>>(A, AT16);
    k_precompP<<<256, 512, 0, stream>>>(AT16, W3T, PT16);
    k_init<<<256, 256, 0, stream>>>(A, Zh0, c, Sc0, Sc1, Sc2);
    for (int t = 0; t < T_; t++) {
        f16* Zin  = (t & 1) ? Zh1 : Zh0;
        f16* Zout = (t & 1) ? Zh0 : Zh1;
        k_step<<<256, 512, 0, stream>>>(x16, W3T, Zin, Zout, A16, PT16, b, c,
                                        Sc[t % 3], Sc[(t + 1) % 3], Sc[(t + 2) % 3],
                                        out, t);
    }
}

// Round 5
// 2019.621 us; speedup vs baseline: 1.8973x; 1.1524x over previous
//
#include <hip/hip_runtime.h>

typedef _Float16 f16;
typedef _Float16 f16x2 __attribute__((ext_vector_type(2)));
typedef _Float16 f16x4 __attribute__((ext_vector_type(4)));
typedef _Float16 f16x8 __attribute__((ext_vector_type(8)));
typedef float f32x4 __attribute__((ext_vector_type(4)));

#define N_ 256
#define T_ 64
#define D_ 1024
#define H_ 1024
#define K3 3072
#define G4 4096

// ---------------- transpose Wx/Wh/Wattn (fp32, [k][j]) -> W3T (fp16, [j][k]) -----
__global__ void k_transpose(const float* __restrict__ Wx, const float* __restrict__ Wh,
                            const float* __restrict__ Wattn, f16* __restrict__ W3T) {
    __shared__ float tile[32][33];
    int j0 = blockIdx.x * 32;   // 128 blocks over j (4096)
    int k0 = blockIdx.y * 32;   // 96 blocks over k (3072)
    int tx = threadIdx.x;       // 32
    int ty = threadIdx.y;       // 8
    for (int i = 0; i < 4; i++) {
        int k = k0 + ty + i * 8;
        const float* W = (k < 1024) ? Wx : ((k < 2048) ? Wh : Wattn);
        int kr = k & 1023;
        tile[ty + i * 8][tx] = W[(size_t)kr * 4096 + j0 + tx];
    }
    __syncthreads();
    for (int i = 0; i < 4; i++) {
        int j = j0 + ty + i * 8;
        W3T[(size_t)j * K3 + k0 + tx] = (f16)tile[tx][ty + i * 8];
    }
}

// ---------------- cast x (fp32) -> x16 (f16), 8 elems/thread ---------------------
__global__ void k_castX(const float* __restrict__ x, f16* __restrict__ x16) {
    size_t i = (size_t)blockIdx.x * 2048 + (size_t)threadIdx.x * 8;
    float4 v0 = *(const float4*)(x + i);
    float4 v1 = *(const float4*)(x + i + 4);
    f16x8 h;
    h[0] = (f16)v0.x; h[1] = (f16)v0.y; h[2] = (f16)v0.z; h[3] = (f16)v0.w;
    h[4] = (f16)v1.x; h[5] = (f16)v1.y; h[6] = (f16)v1.z; h[7] = (f16)v1.w;
    *(f16x8*)(x16 + i) = h;
}

// ---------------- A (fp32 [n][h][l]) -> A16 [n][h][l] AND AT16 [n][l][h] ---------
__global__ void k_castAT(const float* __restrict__ A, f16* __restrict__ A16,
                         f16* __restrict__ AT16) {
    __shared__ f16 sA[16 * 1024];
    int n = blockIdx.x;
    int tid = threadIdx.x;
    for (int i = 0; i < 4; i++) {
        int h = tid + i * 256;
        const float* Ap = A + (size_t)n * 16384 + h * 16;
        float4 v0 = ((const float4*)Ap)[0];
        float4 v1 = ((const float4*)Ap)[1];
        float4 v2 = ((const float4*)Ap)[2];
        float4 v3 = ((const float4*)Ap)[3];
        float vv[16] = {v0.x, v0.y, v0.z, v0.w, v1.x, v1.y, v1.z, v1.w,
                        v2.x, v2.y, v2.z, v2.w, v3.x, v3.y, v3.z, v3.w};
        f16x8 lo, hi;
#pragma unroll
        for (int l = 0; l < 8; l++) { lo[l] = (f16)vv[l]; hi[l] = (f16)vv[l + 8]; }
        *(f16x8*)(A16 + (size_t)n * 16384 + h * 16) = lo;
        *(f16x8*)(A16 + (size_t)n * 16384 + h * 16 + 8) = hi;
#pragma unroll
        for (int l = 0; l < 16; l++) sA[l * 1024 + h] = (f16)vv[l];
    }
    __syncthreads();
    for (int i = 0; i < 8; i++) {
        int cnk = tid + i * 256;     // 2048 chunks of 8 f16
        f16x8 v = *(const f16x8*)(sA + cnk * 8);
        *(f16x8*)(AT16 + (size_t)n * 16384 + cnk * 8) = v;
    }
}

// ---------------- precompute PT16[n][j][l] = sum_h A[n,h,l] * Wattn[h,j] ---------
// v2: real GEMM structure. grid 1024 = 32 nb(8n) x 32 jb(128j); 8 waves, wave w
// owns 16 j-cols. A chunk (8n x 16l x 256k) staged in LDS once per block, reused
// by all 8 waves; B chunk held in registers (bb[8]), read once per wave; 8
// independent accumulator chains hide MFMA latency.
__global__ __launch_bounds__(512, 4) void k_precompP(
    const f16* __restrict__ AT16, const f16* __restrict__ W3T,
    f16* __restrict__ PT16) {
    __shared__ f16 As[8 * 16 * 264];      // 67.6 KB, k-dim padded 256->264
    int tid = threadIdx.x;
    int wave = tid >> 6;
    int lane = tid & 63;
    int m16 = lane & 15;
    int quad = lane >> 4;
    int bid = blockIdx.x;
    int jb = bid & 31;
    int nb = bid >> 5;
    int n0g = nb * 8;
    int j16 = jb * 128 + wave * 16;

    const f16* bp = W3T + (size_t)(j16 + m16) * K3 + 2048 + quad * 8;

    f32x4 acc[8];
#pragma unroll
    for (int n = 0; n < 8; n++) acc[n] = (f32x4){0.f, 0.f, 0.f, 0.f};

    for (int kb = 0; kb < 4; kb++) {
        __syncthreads();
        // stage A chunk: 8n x 16l x 256k = 64 KB, 4096 16B-chunks, 8 per thread
        for (int i = 0; i < 8; i++) {
            int cidx = tid + i * 512;
            int n  = cidx >> 9;
            int r  = cidx & 511;
            int l  = r >> 5;
            int kc = r & 31;
            f16x8 v = *(const f16x8*)(AT16 + (size_t)(n0g + n) * 16384 + l * 1024 + kb * 256 + kc * 8);
            *(f16x8*)(&As[(n * 16 + l) * 264 + kc * 8]) = v;
        }
        __syncthreads();
        // B chunk to registers: 8 x f16x8 (32 VGPR), read once per wave per chunk
        f16x8 bb[8];
#pragma unroll
        for (int ks = 0; ks < 8; ks++)
            bb[ks] = *(const f16x8*)(bp + kb * 256 + ks * 32);
        // 8 independent chains over n
#pragma unroll
        for (int n = 0; n < 8; n++) {
            const f16* ap = &As[(n * 16 + m16) * 264 + quad * 8];
#pragma unroll
            for (int ks = 0; ks < 8; ks++) {
                f16x8 a = *(const f16x8*)(ap + ks * 32);
                acc[n] = __builtin_amdgcn_mfma_f32_16x16x32_f16(a, bb[ks], acc[n], 0, 0, 0);
            }
        }
    }

    // C layout: col = m16 (j), row = quad*4 + r (l). 8B store per lane per n.
#pragma unroll
    for (int n = 0; n < 8; n++) {
        f16x4 o = {(f16)acc[n][0], (f16)acc[n][1], (f16)acc[n][2], (f16)acc[n][3]};
        *(f16x4*)(PT16 + (size_t)(n0g + n) * 65536 + (size_t)(j16 + m16) * 16 + quad * 4) = o;
    }
}

// ---------------- init: h0 = c0 = mean(A); Sc0[n][:] = h0.A; zero Sc1/Sc2 --------
__global__ void k_init(const float* __restrict__ A, f16* __restrict__ Zh,
                       float* __restrict__ c, float* __restrict__ Sc0,
                       float* __restrict__ Sc1, float* __restrict__ Sc2) {
    int n = blockIdx.x;
    int tid = threadIdx.x;
    __shared__ float sred[256][16];
    float s[16];
#pragma unroll
    for (int l = 0; l < 16; l++) s[l] = 0.f;
    for (int i = 0; i < 4; i++) {
        int h = tid + i * 256;
        const float* Ap = A + (size_t)n * 16384 + h * 16;
        float a[16];
        float sum = 0.f;
#pragma unroll
        for (int l = 0; l < 16; l++) { a[l] = Ap[l]; sum += a[l]; }
        float h0 = sum * (1.f / 16.f);
        c[n * 1024 + h] = h0;
        Zh[n * 1024 + h] = (f16)h0;
#pragma unroll
        for (int l = 0; l < 16; l++) s[l] += h0 * a[l];
    }
#pragma unroll
    for (int l = 0; l < 16; l++) sred[tid][l] = s[l];
    __syncthreads();
    for (int st = 128; st > 0; st >>= 1) {
        if (tid < st) {
#pragma unroll
            for (int l = 0; l < 16; l++) sred[tid][l] += sred[tid + st][l];
        }
        __syncthreads();
    }
    if (tid < 16) {
        Sc0[n * 16 + tid] = sred[0][tid];
        Sc1[n * 16 + tid] = 0.f;
        Sc2[n * 16 + tid] = 0.f;
    }
}

// ---------------- one LSTM step: softmax + GEMM(K=2048) + P-dot + state ----------
// grid 256 = 4 n0(64) x 64 ht(16 h-cols); block 512 = 8 waves.
// Rbuf: reduced scores for THIS step (complete; written by dispatch t-1).
// Wbuf: accumulate partial scores for step t+1 (atomicAdd, device scope).
// Zbuf: zeroed here; it is Wbuf of step t+1. All ordering via dispatch boundaries.
// GEMM: waves 0-3 own x@Wx K-slices, waves 4-7 own h@Wh K-slices (256 K each).
// attn@Wattn is replaced by att(n,j) = sum_l w[n,l]*PT16[n][j][l] in the epilogue.
__global__ __launch_bounds__(512, 2) void k_step(
    const f16* __restrict__ x16, const f16* __restrict__ W3T,
    const f16* __restrict__ Zin, f16* __restrict__ Zout,
    const f16* __restrict__ A16, const f16* __restrict__ PT16,
    const float* __restrict__ b, float* __restrict__ c,
    const float* __restrict__ Rbuf, float* __restrict__ Wbuf,
    float* __restrict__ Zbuf, float* __restrict__ out, int t) {
    __shared__ float Gs[4][4][64 * 17];   // 69.6 KB
    __shared__ float Hs[64 * 17];         //  4.4 KB
    __shared__ float Ws[64][17];          //  4.4 KB softmax weights

    int tid = threadIdx.x;
    int wave = tid >> 6;
    int lane = tid & 63;
    int m16 = lane & 15;
    int quad = lane >> 4;
    int bid = blockIdx.x;
    int ht = bid & 63;
    int n0 = (bid >> 6) << 6;
    int hc = ht * 16;

    // ---- phase A: softmax of reduced scores (64 threads, one n each) ----
    if (tid < 64) {
        const float* rp = Rbuf + (size_t)(n0 + tid) * 16;
        float4 q0 = ((const float4*)rp)[0];
        float4 q1 = ((const float4*)rp)[1];
        float4 q2 = ((const float4*)rp)[2];
        float4 q3 = ((const float4*)rp)[3];
        float v[16] = {q0.x, q0.y, q0.z, q0.w, q1.x, q1.y, q1.z, q1.w,
                       q2.x, q2.y, q2.z, q2.w, q3.x, q3.y, q3.z, q3.w};
        float mx = -1e30f;
#pragma unroll
        for (int l = 0; l < 16; l++) { v[l] *= 0.03125f; mx = fmaxf(mx, v[l]); }
        float sum = 0.f;
#pragma unroll
        for (int l = 0; l < 16; l++) { v[l] = __expf(v[l] - mx); sum += v[l]; }
        float inv = 1.f / sum;
#pragma unroll
        for (int l = 0; l < 16; l++) Ws[tid][l] = v[l] * inv;
    }
    // zero this block's row of the t+2 score buffer (nobody touches it this step)
    if (tid < 16) Zbuf[bid * 16 + tid] = 0.f;

    // ---- GEMM K=2048: waves 0-3 x-segment, waves 4-7 h-segment ----
    f32x4 acc[4][4];
#pragma unroll
    for (int g = 0; g < 4; g++)
#pragma unroll
        for (int m = 0; m < 4; m++) acc[g][m] = (f32x4){0.f, 0.f, 0.f, 0.f};

    int kb = (wave & 3) * 256;
    const f16* ab;
    size_t aoff[4];
    int bc0;
    if (wave < 4) {
        ab = x16 + (size_t)t * 1024 + kb + quad * 8;
#pragma unroll
        for (int mt = 0; mt < 4; mt++)
            aoff[mt] = (size_t)(n0 + mt * 16 + m16) * (T_ * 1024);
        bc0 = kb;
    } else {
        ab = Zin + kb + quad * 8;
#pragma unroll
        for (int mt = 0; mt < 4; mt++)
            aoff[mt] = (size_t)(n0 + mt * 16 + m16) * 1024;
        bc0 = 1024 + kb;
    }
    const f16* brow[4];
#pragma unroll
    for (int g = 0; g < 4; g++)
        brow[g] = W3T + (size_t)(g * 1024 + hc + m16) * K3 + bc0 + quad * 8;

#pragma unroll 2
    for (int s = 0; s < 8; s++) {
        int k = s * 32;
        f16x8 a[4], bb[4];
#pragma unroll
        for (int mt = 0; mt < 4; mt++) a[mt] = *(const f16x8*)(ab + aoff[mt] + k);
#pragma unroll
        for (int g = 0; g < 4; g++) bb[g] = *(const f16x8*)(brow[g] + k);
#pragma unroll
        for (int g = 0; g < 4; g++)
#pragma unroll
            for (int mt = 0; mt < 4; mt++)
                acc[g][mt] = __builtin_amdgcn_mfma_f32_16x16x32_f16(a[mt], bb[g], acc[g][mt], 0, 0, 0);
    }

    // ---- reduce 8 K-slice waves via 4 slabs: write then owner-add ----
    if (wave < 4) {
#pragma unroll
        for (int g = 0; g < 4; g++)
#pragma unroll
            for (int mt = 0; mt < 4; mt++)
#pragma unroll
                for (int r = 0; r < 4; r++)
                    Gs[wave][g][(mt * 16 + quad * 4 + r) * 17 + m16] = acc[g][mt][r];
    }
    __syncthreads();
    if (wave >= 4) {
        int sl = wave - 4;
#pragma unroll
        for (int g = 0; g < 4; g++)
#pragma unroll
            for (int mt = 0; mt < 4; mt++)
#pragma unroll
                for (int r = 0; r < 4; r++)
                    Gs[sl][g][(mt * 16 + quad * 4 + r) * 17 + m16] += acc[g][mt][r];
    }
    __syncthreads();

    // ---- gates + state: thread owns (nn, 2 adjacent h-cols) x 4 gates ----
    {
        int idx0 = tid * 2;
        int nn = idx0 >> 4;
        int hh0 = idx0 & 15;
        int gn = n0 + nn;
        int gh0 = hc + hh0;
        float wv[16];
#pragma unroll
        for (int l = 0; l < 16; l++) wv[l] = Ws[nn][l];
        // attention contribution via PT16: att(g,i) = sum_l wv[l]*PT[gn][g*1024+gh0+i][l]
        float att[4][2];
        const f16* pt = PT16 + (size_t)gn * 65536 + (size_t)gh0 * 16;
#pragma unroll
        for (int g = 0; g < 4; g++)
#pragma unroll
            for (int i = 0; i < 2; i++) {
                const f16* p = pt + ((size_t)g * 1024 + i) * 16;
                f16x8 p0 = *(const f16x8*)(p);
                f16x8 p1 = *(const f16x8*)(p + 8);
                float s = 0.f;
#pragma unroll
                for (int l = 0; l < 8; l++)
                    s += (float)p0[l] * wv[l] + (float)p1[l] * wv[l + 8];
                att[g][i] = s;
            }
        float hn2[2];
#pragma unroll
        for (int i = 0; i < 2; i++) {
            int gi = nn * 17 + hh0 + i;
            int gh = gh0 + i;
            float ai = Gs[0][0][gi] + Gs[1][0][gi] + Gs[2][0][gi] + Gs[3][0][gi] + b[gh] + att[0][i];
            float af = Gs[0][1][gi] + Gs[1][1][gi] + Gs[2][1][gi] + Gs[3][1][gi] + b[1024 + gh] + att[1][i];
            float ao = Gs[0][2][gi] + Gs[1][2][gi] + Gs[2][2][gi] + Gs[3][2][gi] + b[2048 + gh] + att[2][i];
            float ag = Gs[0][3][gi] + Gs[1][3][gi] + Gs[2][3][gi] + Gs[3][3][gi] + b[3072 + gh] + att[3][i];
            float ig = 1.f / (1.f + __expf(-ai));
            float fg = 1.f / (1.f + __expf(-af));
            float og = 1.f / (1.f + __expf(-ao));
            float gg = tanhf(ag);
            float cn = fg * c[gn * 1024 + gh] + ig * gg;
            c[gn * 1024 + gh] = cn;
            float hn = og * tanhf(cn);
            hn2[i] = hn;
            Hs[gi] = hn;
        }
        float2 o2 = {hn2[0], hn2[1]};
        *(float2*)(out + ((size_t)gn * T_ + t) * 1024 + gh0) = o2;
        f16x2 z2 = {(f16)hn2[0], (f16)hn2[1]};
        *(f16x2*)(Zout + gn * 1024 + gh0) = z2;
    }
    __syncthreads();

    // ---- partial scores vs local A16 slice -> atomicAdd into step-t+1 buffer ----
#pragma unroll
    for (int i = 0; i < 2; i++) {
        int idx = i * 512 + tid;
        int nn = idx >> 4;
        int l = idx & 15;
        int gn = n0 + nn;
        const f16* Ap = A16 + (size_t)gn * 16384 + hc * 16 + l;
        float s = 0.f;
#pragma unroll
        for (int hh = 0; hh < 16; hh++)
            s += Hs[nn * 17 + hh] * (float)Ap[hh * 16];
        atomicAdd(Wbuf + gn * 16 + l, s);
    }
}

extern "C" void kernel_launch(void* const* d_in, const int* in_sizes, int n_in,
                              void* d_out, int out_size, void* d_ws, size_t ws_size,
                              hipStream_t stream) {
    const float* x     = (const float*)d_in[0];
    const float* A     = (const float*)d_in[1];
    const float* Wx    = (const float*)d_in[2];
    const float* Wh    = (const float*)d_in[3];
    const float* Wattn = (const float*)d_in[4];
    const float* b     = (const float*)d_in[5];
    float* out = (float*)d_out;

    char* ws = (char*)d_ws;
    size_t off = 0;
    f16* W3T  = (f16*)(ws + off); off += (size_t)G4 * K3 * 2;         // 25.2 MB
    f16* x16  = (f16*)(ws + off); off += (size_t)N_ * T_ * D_ * 2;    // 33.6 MB
    f16* A16  = (f16*)(ws + off); off += (size_t)N_ * H_ * 16 * 2;    //  8.4 MB
    f16* AT16 = (f16*)(ws + off); off += (size_t)N_ * 16 * H_ * 2;    //  8.4 MB
    f16* PT16 = (f16*)(ws + off); off += (size_t)N_ * G4 * 16 * 2;    // 33.6 MB
    f16* Zh0  = (f16*)(ws + off); off += (size_t)N_ * H_ * 2;
    f16* Zh1  = (f16*)(ws + off); off += (size_t)N_ * H_ * 2;
    float* c  = (float*)(ws + off); off += (size_t)N_ * H_ * 4;       //  1 MB
    float* Sc0 = (float*)(ws + off); off += (size_t)N_ * 16 * 4;      // 16 KB
    float* Sc1 = (float*)(ws + off); off += (size_t)N_ * 16 * 4;
    float* Sc2 = (float*)(ws + off); off += (size_t)N_ * 16 * 4;
    float* Sc[3] = {Sc0, Sc1, Sc2};

    k_transpose<<<dim3(128, 96), dim3(32, 8), 0, stream>>>(Wx, Wh, Wattn, W3T);
    k_castX<<<8192, 256, 0, stream>>>(x, x16);
    k_castAT<<<256, 256, 0, stream>>>(A, A16, AT16);
    k_precompP<<<1024, 512, 0, stream>>>(AT16, W3T, PT16);
    k_init<<<256, 256, 0, stream>>>(A, Zh0, c, Sc0, Sc1, Sc2);
    for (int t = 0; t < T_; t++) {
        f16* Zin  = (t & 1) ? Zh1 : Zh0;
        f16* Zout = (t & 1) ? Zh0 : Zh1;
        k_step<<<256, 512, 0, stream>>>(x16, W3T, Zin, Zout, A16, PT16, b, c,
                                        Sc[t % 3], Sc[(t + 1) % 3], Sc[(t + 2) % 3],
                                        out, t);
    }
}